// Round 1
// baseline (812.251 us; speedup 1.0000x reference)
//
#include <hip/hip_runtime.h>
#include <math.h>

// ---------------- workspace layout (bytes) ----------------
#define OFF_SIMKEY   0          // u64[8]
#define OFF_POOLED   1024       // f32[8*512]
#define OFF_SSD      32768      // f32[65536]
#define OFF_NX2      294912     // f32[65536]
#define OFF_DOT      557056     // f32[65536]
#define ZEROED_BYTES 819200
#define OFF_MAXSIM   819200     // f32[8]
#define OFF_NORME    819456     // f32[8]
#define OFF_EBEST    819712     // f32[8*512]
#define OFF_BPRIME   836608     // f32[512]
#define OFF_WP       839680     // bf16[512*512]  (W' = W1 @ Wc)
#define OFF_W2B      1364992    // bf16[512*512]
#define OFF_H        1900544    // bf16[65536*512]  (64 MB)

typedef __attribute__((ext_vector_type(8))) short bf16x8;
typedef __attribute__((ext_vector_type(4))) float f32x4;

__device__ inline unsigned short f2bf(float f) {
    unsigned int u = __float_as_uint(f);
    unsigned int r = (u + 0x7FFFu + ((u >> 16) & 1u)) >> 16;
    return (unsigned short)r;
}

__device__ inline void load_lds_16(const void* g, void* l) {
    __builtin_amdgcn_global_load_lds((const __attribute__((address_space(1))) void*)g,
                                     (__attribute__((address_space(3))) void*)l, 16, 0, 0);
}

// ---------------- W' = W1 @ Wc (bf16), b' = b1 + W1 @ bc ----------------
__global__ void __launch_bounds__(256) k_pre(const float* __restrict__ W1, const float* __restrict__ Wc,
                      const float* __restrict__ b1, const float* __restrict__ bc,
                      unsigned short* __restrict__ Wp, float* __restrict__ bprime) {
    __shared__ float w1s[8 * 512];
    int t = threadIdx.x;
    int n0 = blockIdx.x * 8;
    const float4* src = (const float4*)(W1 + (size_t)n0 * 512);
    float4* dst = (float4*)w1s;
#pragma unroll
    for (int c = 0; c < 4; ++c) dst[t + c * 256] = src[t + c * 256];
    __syncthreads();
    int k0 = t, k1 = t + 256;
    float acc0[8], acc1[8];
#pragma unroll
    for (int n = 0; n < 8; ++n) { acc0[n] = 0.f; acc1[n] = 0.f; }
    for (int j = 0; j < 512; ++j) {
        float a = Wc[(size_t)j * 512 + k0];
        float b = Wc[(size_t)j * 512 + k1];
#pragma unroll
        for (int n = 0; n < 8; ++n) {
            float w = w1s[n * 512 + j];
            acc0[n] += w * a; acc1[n] += w * b;
        }
    }
#pragma unroll
    for (int n = 0; n < 8; ++n) {
        Wp[(size_t)(n0 + n) * 512 + k0] = f2bf(acc0[n]);
        Wp[(size_t)(n0 + n) * 512 + k1] = f2bf(acc1[n]);
    }
    int nl = t >> 5, l32 = t & 31;
    float p = 0.f;
    for (int j = l32; j < 512; j += 32) p += w1s[nl * 512 + j] * bc[j];
#pragma unroll
    for (int m = 16; m >= 1; m >>= 1) p += __shfl_xor(p, m);
    if (l32 == 0) bprime[n0 + nl] = b1[n0 + nl] + p;
}

// ---------------- W2 -> bf16 ----------------
__global__ void __launch_bounds__(256) k_cast(const float* __restrict__ W2, unsigned short* __restrict__ W2b) {
    int i = blockIdx.x * 1024 + threadIdx.x * 4;
    float4 v = *(const float4*)(W2 + i);
    ushort4 o;
    o.x = f2bf(v.x); o.y = f2bf(v.y); o.z = f2bf(v.z); o.w = f2bf(v.w);
    *(ushort4*)(W2b + i) = o;
}

// ---------------- pooled sum over L ----------------
__global__ void __launch_bounds__(512) k_pool(const float* __restrict__ x, float* __restrict__ pooled) {
    int d = threadIdx.x;
    int b = blockIdx.y;
    int l0 = blockIdx.x * 128;
    const float* p = x + ((size_t)b * 8192 + l0) * 512 + d;
    float s = 0.f;
    for (int i = 0; i < 128; ++i) s += p[(size_t)i * 512];
    atomicAdd(&pooled[b * 512 + d], s);
}

// ---------------- sim scan: argmax cos(pooled_b, E_s) over active s ----------------
__global__ void __launch_bounds__(256) k_sim(const float* __restrict__ E, const float* __restrict__ sl,
                     const float* __restrict__ pooledws, unsigned long long* __restrict__ simkey) {
    __shared__ float ps[4096];
    __shared__ unsigned long long wkey[4][8];
    int t = threadIdx.x, lane = t & 63, w = t >> 6;
#pragma unroll
    for (int c = 0; c < 16; ++c) ps[t + c * 256] = pooledws[t + c * 256] * (1.0f / 8192.0f);
    __syncthreads();
    float pr[8][8];
#pragma unroll
    for (int b = 0; b < 8; ++b) {
        float4 v0 = *(const float4*)&ps[b * 512 + lane * 8];
        float4 v1 = *(const float4*)&ps[b * 512 + lane * 8 + 4];
        pr[b][0] = v0.x; pr[b][1] = v0.y; pr[b][2] = v0.z; pr[b][3] = v0.w;
        pr[b][4] = v1.x; pr[b][5] = v1.y; pr[b][6] = v1.z; pr[b][7] = v1.w;
    }
    float npinv[8];
#pragma unroll
    for (int b = 0; b < 8; ++b) {
        float s = 0.f;
#pragma unroll
        for (int j = 0; j < 8; ++j) s += pr[b][j] * pr[b][j];
#pragma unroll
        for (int m = 32; m >= 1; m >>= 1) s += __shfl_xor(s, m);
        npinv[b] = 1.0f / fmaxf(sqrtf(s), 1e-8f);
    }
    unsigned long long best[8];
#pragma unroll
    for (int b = 0; b < 8; ++b) best[b] = 0ull;
    int sbase = blockIdx.x * 512 + w * 128;
    for (int g = 0; g < 2; ++g) {
        float mysl = sl[sbase + g * 64 + lane];
        unsigned long long mask = __ballot(mysl > 0.0f);
        for (int it = 0; it < 64; ++it) {
            if (!((mask >> it) & 1ull)) continue;
            int s = sbase + g * 64 + it;
            const float4* ep = (const float4*)(E + (size_t)s * 512);
            float4 e0 = ep[lane * 2], e1 = ep[lane * 2 + 1];
            float nrm = e0.x * e0.x + e0.y * e0.y + e0.z * e0.z + e0.w * e0.w
                      + e1.x * e1.x + e1.y * e1.y + e1.z * e1.z + e1.w * e1.w;
            float dt[8];
#pragma unroll
            for (int b = 0; b < 8; ++b)
                dt[b] = e0.x * pr[b][0] + e0.y * pr[b][1] + e0.z * pr[b][2] + e0.w * pr[b][3]
                      + e1.x * pr[b][4] + e1.y * pr[b][5] + e1.z * pr[b][6] + e1.w * pr[b][7];
#pragma unroll
            for (int m = 32; m >= 1; m >>= 1) {
                nrm += __shfl_xor(nrm, m);
#pragma unroll
                for (int b = 0; b < 8; ++b) dt[b] += __shfl_xor(dt[b], m);
            }
            float neinv = 1.0f / fmaxf(sqrtf(nrm), 1e-8f);
#pragma unroll
            for (int b = 0; b < 8; ++b) {
                float sim = dt[b] * npinv[b] * neinv;
                unsigned int u = __float_as_uint(sim);
                unsigned int k32 = (u & 0x80000000u) ? ~u : (u | 0x80000000u);
                unsigned long long key = ((unsigned long long)k32 << 32) | (unsigned int)(~(unsigned int)s);
                if (key > best[b]) best[b] = key;
            }
        }
    }
    if (lane == 0) {
#pragma unroll
        for (int b = 0; b < 8; ++b) wkey[w][b] = best[b];
    }
    __syncthreads();
    if (t < 8) {
        unsigned long long k = wkey[0][t];
#pragma unroll
        for (int w2 = 1; w2 < 4; ++w2) if (wkey[w2][t] > k) k = wkey[w2][t];
        if (k) atomicMax(&simkey[t], k);
    }
}

// ---------------- decode best, gather embedding + norm ----------------
__global__ void __launch_bounds__(64) k_b2(const float* __restrict__ E, const unsigned long long* __restrict__ simkey,
                    float* __restrict__ max_sim, float* __restrict__ norm_e, float* __restrict__ ebest) {
    int b = blockIdx.x, lane = threadIdx.x;
    unsigned long long key = simkey[b];
    float ms; unsigned int idx;
    if (key == 0ull) { ms = -1e30f; idx = 0u; }
    else {
        unsigned int k32 = (unsigned int)(key >> 32);
        unsigned int u = (k32 & 0x80000000u) ? (k32 & 0x7FFFFFFFu) : ~k32;
        ms = __uint_as_float(u);
        idx = ~(unsigned int)(key & 0xFFFFFFFFull);
    }
    const float4* ep = (const float4*)(E + (size_t)idx * 512);
    float4 e0 = ep[lane * 2], e1 = ep[lane * 2 + 1];
    *(float4*)&ebest[b * 512 + lane * 8] = e0;
    *(float4*)&ebest[b * 512 + lane * 8 + 4] = e1;
    float s = e0.x * e0.x + e0.y * e0.y + e0.z * e0.z + e0.w * e0.w
            + e1.x * e1.x + e1.y * e1.y + e1.z * e1.z + e1.w * e1.w;
#pragma unroll
    for (int m = 32; m >= 1; m >>= 1) s += __shfl_xor(s, m);
    if (lane == 0) { max_sim[b] = ms; norm_e[b] = fmaxf(sqrtf(s), 1e-8f); }
}

// ---------------- GEMM1: H = gelu(context @ W'^T + b')  (bf16 out) ----------------
__global__ void __launch_bounds__(256) k_gemm1(const float* __restrict__ x, const unsigned short* __restrict__ Wp,
                        const float* __restrict__ bprime, unsigned short* __restrict__ H) {
    __shared__ char smem[32768];
    unsigned short* As = (unsigned short*)smem;            // [128][32] bf16
    unsigned short* Bs = (unsigned short*)(smem + 8192);   // [128][32] bf16
    int t = threadIdx.x, lane = t & 63, w = t >> 6, l15 = lane & 15, quad = lane >> 4;
    int cb = blockIdx.x, rb = blockIdx.y;
    int wr = w >> 1, wc = w & 1;
    f32x4 acc[4][4];
#pragma unroll
    for (int i = 0; i < 4; ++i)
#pragma unroll
        for (int j = 0; j < 4; ++j) acc[i][j] = (f32x4){0.f, 0.f, 0.f, 0.f};
    const int gr0 = rb * 128;
    for (int kt = 0; kt < 16; ++kt) {
        __syncthreads();
        // stage A: fp32 -> bf16 (causal shift: context[l] = x[l-1], 0 at l==0)
#pragma unroll
        for (int c = 0; c < 4; ++c) {
            int u = c * 256 + t;
            int row = u >> 3, f4 = u & 7;
            int gr = gr0 + row;
            int l = gr & 8191;
            float4 v = make_float4(0.f, 0.f, 0.f, 0.f);
            if (l != 0) v = *(const float4*)(x + ((size_t)gr - 1) * 512 + kt * 32 + f4 * 4);
            ushort4 o;
            o.x = f2bf(v.x); o.y = f2bf(v.y); o.z = f2bf(v.z); o.w = f2bf(v.w);
            *(ushort4*)&As[row * 32 + f4 * 4] = o;
        }
        // stage B: W' tile, async direct-to-LDS
#pragma unroll
        for (int c = 0; c < 2; ++c) {
            int q = w * 2 + c;
            int unit = q * 64 + lane;
            int row = unit >> 2, kb = unit & 3;
            const unsigned short* g = Wp + (size_t)(cb * 128 + row) * 512 + kt * 32 + kb * 8;
            load_lds_16(g, Bs + q * 512);
        }
        __syncthreads();
        bf16x8 af[4], bfr[4];
#pragma unroll
        for (int i = 0; i < 4; ++i)
            af[i] = *(const bf16x8*)&As[(wr * 64 + i * 16 + l15) * 32 + quad * 8];
#pragma unroll
        for (int j = 0; j < 4; ++j)
            bfr[j] = *(const bf16x8*)&Bs[(wc * 64 + j * 16 + l15) * 32 + quad * 8];
#pragma unroll
        for (int i = 0; i < 4; ++i)
#pragma unroll
            for (int j = 0; j < 4; ++j)
                acc[i][j] = __builtin_amdgcn_mfma_f32_16x16x32_bf16(af[i], bfr[j], acc[i][j], 0, 0, 0);
    }
    __syncthreads();
    float bpj[4];
#pragma unroll
    for (int j = 0; j < 4; ++j) bpj[j] = bprime[cb * 128 + wc * 64 + j * 16 + l15];
    unsigned short* hs = (unsigned short*)smem; // [128][128] bf16
#pragma unroll
    for (int i = 0; i < 4; ++i)
#pragma unroll
        for (int j = 0; j < 4; ++j)
#pragma unroll
            for (int r = 0; r < 4; ++r) {
                int m = wr * 64 + i * 16 + quad * 4 + r;
                int n = wc * 64 + j * 16 + l15;
                float v = acc[i][j][r] + bpj[j];
                v = 0.5f * v * (1.0f + erff(v * 0.70710678118f));  // exact gelu
                hs[m * 128 + n] = f2bf(v);
            }
    __syncthreads();
    {
        int row = t >> 1, half = t & 1;
        const uint4* srcp = (const uint4*)(smem + row * 256 + half * 128);
        uint4* dstp = (uint4*)((char*)H + ((size_t)(gr0 + row)) * 1024 + cb * 256 + half * 128);
#pragma unroll
        for (int u2 = 0; u2 < 8; ++u2) dstp[u2] = srcp[u2];
    }
}

// ---------------- GEMM2: P = H @ W2^T + b2, fused row reductions ----------------
__global__ void __launch_bounds__(256) k_gemm2(const unsigned short* __restrict__ H, const unsigned short* __restrict__ W2b,
                        const float* __restrict__ b2, const float* __restrict__ x,
                        const float* __restrict__ ebest,
                        float* __restrict__ ssd, float* __restrict__ nx2, float* __restrict__ xdot) {
    __shared__ char smem[16384];
    unsigned short* As = (unsigned short*)smem;
    unsigned short* Bs = (unsigned short*)(smem + 8192);
    int t = threadIdx.x, lane = t & 63, w = t >> 6, l15 = lane & 15, quad = lane >> 4;
    int cb = blockIdx.x, rb = blockIdx.y;
    int wr = w >> 1, wc = w & 1;
    f32x4 acc[4][4];
#pragma unroll
    for (int i = 0; i < 4; ++i)
#pragma unroll
        for (int j = 0; j < 4; ++j) acc[i][j] = (f32x4){0.f, 0.f, 0.f, 0.f};
    const int gr0 = rb * 128;
    for (int kt = 0; kt < 16; ++kt) {
        __syncthreads();
#pragma unroll
        for (int c = 0; c < 2; ++c) {
            int q = w * 2 + c;
            int unit = q * 64 + lane;
            int row = unit >> 2, kb = unit & 3;
            const unsigned short* gA = H + (size_t)(gr0 + row) * 512 + kt * 32 + kb * 8;
            load_lds_16(gA, As + q * 512);
            const unsigned short* gB = W2b + (size_t)(cb * 128 + row) * 512 + kt * 32 + kb * 8;
            load_lds_16(gB, Bs + q * 512);
        }
        __syncthreads();
        bf16x8 af[4], bfr[4];
#pragma unroll
        for (int i = 0; i < 4; ++i)
            af[i] = *(const bf16x8*)&As[(wr * 64 + i * 16 + l15) * 32 + quad * 8];
#pragma unroll
        for (int j = 0; j < 4; ++j)
            bfr[j] = *(const bf16x8*)&Bs[(wc * 64 + j * 16 + l15) * 32 + quad * 8];
#pragma unroll
        for (int i = 0; i < 4; ++i)
#pragma unroll
            for (int j = 0; j < 4; ++j)
                acc[i][j] = __builtin_amdgcn_mfma_f32_16x16x32_bf16(af[i], bfr[j], acc[i][j], 0, 0, 0);
    }
    // epilogue: per-row partial sums over this col-slice
    int b = gr0 >> 13;
    float b2j[4], ej[4];
#pragma unroll
    for (int j = 0; j < 4; ++j) {
        int n = cb * 128 + wc * 64 + j * 16 + l15;
        b2j[j] = b2[n];
        ej[j] = ebest[b * 512 + n];
    }
#pragma unroll
    for (int i = 0; i < 4; ++i)
#pragma unroll
        for (int r = 0; r < 4; ++r) {
            int gr = gr0 + wr * 64 + i * 16 + quad * 4 + r;
            float sd = 0.f, sx = 0.f, sdt = 0.f;
#pragma unroll
            for (int j = 0; j < 4; ++j) {
                int n = cb * 128 + wc * 64 + j * 16 + l15;
                float p = acc[i][j][r] + b2j[j];
                float xv = x[(size_t)gr * 512 + n];
                float d = xv - p;
                sd += d * d; sx += xv * xv; sdt += xv * ej[j];
            }
#pragma unroll
            for (int m = 8; m >= 1; m >>= 1) {
                sd += __shfl_xor(sd, m);
                sx += __shfl_xor(sx, m);
                sdt += __shfl_xor(sdt, m);
            }
            if (l15 == 0) {
                atomicAdd(&ssd[gr], sd);
                atomicAdd(&nx2[gr], sx);
                atomicAdd(&xdot[gr], sdt);
            }
        }
}

// ---------------- final combine ----------------
__global__ void __launch_bounds__(256) k_final(const float* __restrict__ ssd, const float* __restrict__ nx2,
                        const float* __restrict__ xdot, const float* __restrict__ max_sim,
                        const float* __restrict__ norm_e, float* __restrict__ out) {
    int r = blockIdx.x * 256 + threadIdx.x;
    int b = r >> 13;
    float ps = sqrtf(ssd[r] * (1.0f / 512.0f));
    float ms = max_sim[b];
    float c = 0.0f;
    if (ms > 0.3f) {
        float nx = fmaxf(sqrtf(nx2[r]), 1e-8f);
        float cs = xdot[r] / (nx * norm_e[b]);
        c = 2.0f * (1.0f - cs);
    }
    out[r] = fmaxf(ps, c);
}

extern "C" void kernel_launch(void* const* d_in, const int* in_sizes, int n_in,
                              void* d_out, int out_size, void* d_ws, size_t ws_size,
                              hipStream_t stream) {
    const float* x  = (const float*)d_in[0];
    const float* Wc = (const float*)d_in[1];
    const float* bc = (const float*)d_in[2];
    const float* W1 = (const float*)d_in[3];
    const float* b1 = (const float*)d_in[4];
    const float* W2 = (const float*)d_in[5];
    const float* b2 = (const float*)d_in[6];
    const float* E  = (const float*)d_in[7];
    const float* sl = (const float*)d_in[8];

    char* ws = (char*)d_ws;
    unsigned long long* simkey = (unsigned long long*)(ws + OFF_SIMKEY);
    float* pooled  = (float*)(ws + OFF_POOLED);
    float* ssd     = (float*)(ws + OFF_SSD);
    float* nx2     = (float*)(ws + OFF_NX2);
    float* xdot    = (float*)(ws + OFF_DOT);
    float* max_sim = (float*)(ws + OFF_MAXSIM);
    float* norm_e  = (float*)(ws + OFF_NORME);
    float* ebest   = (float*)(ws + OFF_EBEST);
    float* bprime  = (float*)(ws + OFF_BPRIME);
    unsigned short* Wp  = (unsigned short*)(ws + OFF_WP);
    unsigned short* W2b = (unsigned short*)(ws + OFF_W2B);
    unsigned short* H   = (unsigned short*)(ws + OFF_H);
    float* out = (float*)d_out;

    hipMemsetAsync(ws, 0, ZEROED_BYTES, stream);
    k_pre<<<64, 256, 0, stream>>>(W1, Wc, b1, bc, Wp, bprime);
    k_cast<<<256, 256, 0, stream>>>(W2, W2b);
    k_pool<<<dim3(64, 8), 512, 0, stream>>>(x, pooled);
    k_sim<<<256, 256, 0, stream>>>(E, sl, pooled, simkey);
    k_b2<<<8, 64, 0, stream>>>(E, simkey, max_sim, norm_e, ebest);
    k_gemm1<<<dim3(4, 512), 256, 0, stream>>>(x, Wp, bprime, H);
    k_gemm2<<<dim3(4, 512), 256, 0, stream>>>(H, W2b, b2, x, ebest, ssd, nx2, xdot);
    k_final<<<256, 256, 0, stream>>>(ssd, nx2, xdot, max_sim, norm_e, out);
}

// Round 2
// 793.442 us; speedup vs baseline: 1.0237x; 1.0237x over previous
//
#include <hip/hip_runtime.h>
#include <math.h>

// ---------------- workspace layout (bytes) ----------------
#define OFF_SIMKEY   0          // u64[8]
#define OFF_POOLED   1024       // f32[8*512]
#define ZEROED_BYTES 17408
#define OFF_MAXSIM   17408      // f32[8]
#define OFF_NORME    17664      // f32[8]
#define OFF_EBEST    17920      // f32[8*512]
#define OFF_BPRIME   34304      // f32[512]
#define OFF_WP       36864      // bf16[512*512]  (W' = W1 @ Wc)
#define OFF_W2B      561152     // bf16[512*512]

typedef __attribute__((ext_vector_type(8))) short bf16x8;
typedef __attribute__((ext_vector_type(4))) float f32x4;

__device__ inline unsigned short f2bf(float f) {
    unsigned int u = __float_as_uint(f);
    unsigned int r = (u + 0x7FFFu + ((u >> 16) & 1u)) >> 16;
    return (unsigned short)r;
}

__device__ inline void load_lds_16(const void* g, void* l) {
    __builtin_amdgcn_global_load_lds((const __attribute__((address_space(1))) void*)g,
                                     (__attribute__((address_space(3))) void*)l, 16, 0, 0);
}

// ---------------- W' = W1 @ Wc (bf16), b' = b1 + W1 @ bc ----------------
// grid 1024: block (n = bid>>1, k-half = bid&1) computes 256 outputs of row n.
__global__ void __launch_bounds__(256) k_pre(const float* __restrict__ W1, const float* __restrict__ Wc,
                      const float* __restrict__ b1, const float* __restrict__ bc,
                      unsigned short* __restrict__ Wp, float* __restrict__ bprime) {
    __shared__ float w1row[512];
    __shared__ float wsum[4];
    int t = threadIdx.x;
    int n = blockIdx.x >> 1, half = blockIdx.x & 1;
    if (t < 128) ((float4*)w1row)[t] = ((const float4*)(W1 + (size_t)n * 512))[t];
    __syncthreads();
    int k = half * 256 + t;
    float acc = 0.f;
#pragma unroll 8
    for (int j = 0; j < 512; ++j) acc += w1row[j] * Wc[(size_t)j * 512 + k];
    Wp[(size_t)n * 512 + k] = f2bf(acc);
    if (half == 0) {
        float p = w1row[t] * bc[t] + w1row[t + 256] * bc[t + 256];
#pragma unroll
        for (int m = 32; m >= 1; m >>= 1) p += __shfl_xor(p, m);
        if ((t & 63) == 0) wsum[t >> 6] = p;
        __syncthreads();
        if (t == 0) bprime[n] = b1[n] + wsum[0] + wsum[1] + wsum[2] + wsum[3];
    }
}

// ---------------- W2 -> bf16 ----------------
__global__ void __launch_bounds__(256) k_cast(const float* __restrict__ W2, unsigned short* __restrict__ W2b) {
    int i = blockIdx.x * 1024 + threadIdx.x * 4;
    float4 v = *(const float4*)(W2 + i);
    ushort4 o;
    o.x = f2bf(v.x); o.y = f2bf(v.y); o.z = f2bf(v.z); o.w = f2bf(v.w);
    *(ushort4*)(W2b + i) = o;
}

// ---------------- pooled sum over L ----------------
__global__ void __launch_bounds__(512) k_pool(const float* __restrict__ x, float* __restrict__ pooled) {
    int d = threadIdx.x;
    int b = blockIdx.y;
    int l0 = blockIdx.x * 128;
    const float* p = x + ((size_t)b * 8192 + l0) * 512 + d;
    float s = 0.f;
    for (int i = 0; i < 128; ++i) s += p[(size_t)i * 512];
    atomicAdd(&pooled[b * 512 + d], s);
}

// ---------------- sim scan: argmax cos(pooled_b, E_s) over active s ----------------
// grid 2048 x 256: 16 slots per wave -> 8 blocks/CU for latency hiding.
__global__ void __launch_bounds__(256) k_sim(const float* __restrict__ E, const float* __restrict__ sl,
                     const float* __restrict__ pooledws, unsigned long long* __restrict__ simkey) {
    __shared__ float ps[4096];
    __shared__ unsigned long long wkey[4][8];
    int t = threadIdx.x, lane = t & 63, w = t >> 6;
#pragma unroll
    for (int c = 0; c < 16; ++c) ps[t + c * 256] = pooledws[t + c * 256] * (1.0f / 8192.0f);
    __syncthreads();
    float pr[8][8];
#pragma unroll
    for (int b = 0; b < 8; ++b) {
        float4 v0 = *(const float4*)&ps[b * 512 + lane * 8];
        float4 v1 = *(const float4*)&ps[b * 512 + lane * 8 + 4];
        pr[b][0] = v0.x; pr[b][1] = v0.y; pr[b][2] = v0.z; pr[b][3] = v0.w;
        pr[b][4] = v1.x; pr[b][5] = v1.y; pr[b][6] = v1.z; pr[b][7] = v1.w;
    }
    float npinv[8];
#pragma unroll
    for (int b = 0; b < 8; ++b) {
        float s = 0.f;
#pragma unroll
        for (int j = 0; j < 8; ++j) s += pr[b][j] * pr[b][j];
#pragma unroll
        for (int m = 32; m >= 1; m >>= 1) s += __shfl_xor(s, m);
        npinv[b] = 1.0f / fmaxf(sqrtf(s), 1e-8f);
    }
    unsigned long long best[8];
#pragma unroll
    for (int b = 0; b < 8; ++b) best[b] = 0ull;
    int sbase = blockIdx.x * 64 + w * 16;
    float mysl = (lane < 16) ? sl[sbase + lane] : 0.f;
    unsigned long long mask = __ballot(mysl > 0.0f);
    for (int it = 0; it < 16; ++it) {
        if (!((mask >> it) & 1ull)) continue;
        int s = sbase + it;
        const float4* ep = (const float4*)(E + (size_t)s * 512);
        float4 e0 = ep[lane * 2], e1 = ep[lane * 2 + 1];
        float nrm = e0.x * e0.x + e0.y * e0.y + e0.z * e0.z + e0.w * e0.w
                  + e1.x * e1.x + e1.y * e1.y + e1.z * e1.z + e1.w * e1.w;
        float dt[8];
#pragma unroll
        for (int b = 0; b < 8; ++b)
            dt[b] = e0.x * pr[b][0] + e0.y * pr[b][1] + e0.z * pr[b][2] + e0.w * pr[b][3]
                  + e1.x * pr[b][4] + e1.y * pr[b][5] + e1.z * pr[b][6] + e1.w * pr[b][7];
#pragma unroll
        for (int m = 32; m >= 1; m >>= 1) {
            nrm += __shfl_xor(nrm, m);
#pragma unroll
            for (int b = 0; b < 8; ++b) dt[b] += __shfl_xor(dt[b], m);
        }
        float neinv = 1.0f / fmaxf(sqrtf(nrm), 1e-8f);
#pragma unroll
        for (int b = 0; b < 8; ++b) {
            float sim = dt[b] * npinv[b] * neinv;
            unsigned int u = __float_as_uint(sim);
            unsigned int k32 = (u & 0x80000000u) ? ~u : (u | 0x80000000u);
            unsigned long long key = ((unsigned long long)k32 << 32) | (unsigned int)(~(unsigned int)s);
            if (key > best[b]) best[b] = key;
        }
    }
    if (lane == 0) {
#pragma unroll
        for (int b = 0; b < 8; ++b) wkey[w][b] = best[b];
    }
    __syncthreads();
    if (t < 8) {
        unsigned long long k = wkey[0][t];
#pragma unroll
        for (int w2 = 1; w2 < 4; ++w2) if (wkey[w2][t] > k) k = wkey[w2][t];
        if (k) atomicMax(&simkey[t], k);
    }
}

// ---------------- decode best, gather embedding + norm ----------------
__global__ void __launch_bounds__(64) k_b2(const float* __restrict__ E, const unsigned long long* __restrict__ simkey,
                    float* __restrict__ max_sim, float* __restrict__ norm_e, float* __restrict__ ebest) {
    int b = blockIdx.x, lane = threadIdx.x;
    unsigned long long key = simkey[b];
    float ms; unsigned int idx;
    if (key == 0ull) { ms = -1e30f; idx = 0u; }
    else {
        unsigned int k32 = (unsigned int)(key >> 32);
        unsigned int u = (k32 & 0x80000000u) ? (k32 & 0x7FFFFFFFu) : ~k32;
        ms = __uint_as_float(u);
        idx = ~(unsigned int)(key & 0xFFFFFFFFull);
    }
    const float4* ep = (const float4*)(E + (size_t)idx * 512);
    float4 e0 = ep[lane * 2], e1 = ep[lane * 2 + 1];
    *(float4*)&ebest[b * 512 + lane * 8] = e0;
    *(float4*)&ebest[b * 512 + lane * 8 + 4] = e1;
    float s = e0.x * e0.x + e0.y * e0.y + e0.z * e0.z + e0.w * e0.w
            + e1.x * e1.x + e1.y * e1.y + e1.z * e1.z + e1.w * e1.w;
#pragma unroll
    for (int m = 32; m >= 1; m >>= 1) s += __shfl_xor(s, m);
    if (lane == 0) { max_sim[b] = ms; norm_e[b] = fmaxf(sqrtf(s), 1e-8f); }
}

// ---------------- fused: GEMM1 (gelu) -> GEMM2 -> row reductions -> out ----------------
// One block per 64 output rows. A (bf16 context) and H (bf16 hidden) live in VGPRs;
// per-k-step fragments bounce through a 5 KB LDS tile. 32 KB LDS total.
// LDS map: Ts [64][40] bf16 @0 (5120B) | Bs [128][32] bf16 @5120 (8192B)
//          hbuf [64][136] bf16 @13312 (17408B) | red [4][32][4] f32 @30720 (2048B)
__global__ void __launch_bounds__(256, 2) k_fused(
        const float* __restrict__ x, const unsigned short* __restrict__ Wp,
        const float* __restrict__ bprime, const unsigned short* __restrict__ W2b,
        const float* __restrict__ b2, const float* __restrict__ ebest,
        const float* __restrict__ max_sim, const float* __restrict__ norm_e,
        float* __restrict__ out) {
    __shared__ char smem[32768];
    unsigned short* Ts   = (unsigned short*)smem;            // [64][40]
    unsigned short* Bs   = (unsigned short*)(smem + 5120);   // [128][32]
    unsigned short* hbuf = (unsigned short*)(smem + 13312);  // [64][136]
    float* red           = (float*)(smem + 30720);           // [4][32][4]
    int t = threadIdx.x, lane = t & 63, w = t >> 6, l15 = lane & 15, quad = lane >> 4;
    int wr = w >> 1, wc = w & 1;
    const int gr0 = blockIdx.x * 64;
    const int b = gr0 >> 13;
    const int row0 = t >> 3, f4 = t & 7;

    // ---- load A (causal-shifted x rows) into regs as bf16 ----
    ushort4 ush[16][2];
#pragma unroll
    for (int c = 0; c < 2; ++c) {
        int gr = gr0 + row0 + c * 32;
        bool z = ((gr & 8191) == 0);
        const float* src = x + ((size_t)gr - 1) * 512 + f4 * 4;
#pragma unroll
        for (int kt = 0; kt < 16; ++kt) {
            float4 v = make_float4(0.f, 0.f, 0.f, 0.f);
            if (!z) v = *(const float4*)(src + kt * 32);
            ushort4 o;
            o.x = f2bf(v.x); o.y = f2bf(v.y); o.z = f2bf(v.z); o.w = f2bf(v.w);
            ush[kt][c] = o;
        }
    }

    ushort4 hregs[16][2];
    // ================= GEMM1: H = gelu(A @ W'^T + b') =================
#pragma unroll
    for (int cb = 0; cb < 4; ++cb) {
        f32x4 acc[2][4];
#pragma unroll
        for (int i = 0; i < 2; ++i)
#pragma unroll
            for (int j = 0; j < 4; ++j) acc[i][j] = (f32x4){0.f, 0.f, 0.f, 0.f};
#pragma unroll
        for (int kt = 0; kt < 16; ++kt) {
            __syncthreads();
            *(ushort4*)&Ts[row0 * 40 + f4 * 4]        = ush[kt][0];
            *(ushort4*)&Ts[(row0 + 32) * 40 + f4 * 4] = ush[kt][1];
#pragma unroll
            for (int c = 0; c < 2; ++c) {
                int unit = c * 256 + w * 64 + lane;
                int row = unit >> 2, kb = unit & 3;
                load_lds_16(Wp + (size_t)(cb * 128 + row) * 512 + kt * 32 + kb * 8,
                            Bs + (size_t)(c * 256 + w * 64) * 8);
            }
            __syncthreads();
            bf16x8 af[2], bfr[4];
            af[0] = *(const bf16x8*)&Ts[(wr * 32 + l15) * 40 + quad * 8];
            af[1] = *(const bf16x8*)&Ts[(wr * 32 + 16 + l15) * 40 + quad * 8];
#pragma unroll
            for (int j = 0; j < 4; ++j)
                bfr[j] = *(const bf16x8*)&Bs[(wc * 64 + j * 16 + l15) * 32 + quad * 8];
#pragma unroll
            for (int i = 0; i < 2; ++i)
#pragma unroll
                for (int j = 0; j < 4; ++j)
                    acc[i][j] = __builtin_amdgcn_mfma_f32_16x16x32_bf16(af[i], bfr[j], acc[i][j], 0, 0, 0);
        }
        // epilogue: bias + exact gelu -> hbuf (C-layout)
        float bpj[4];
#pragma unroll
        for (int j = 0; j < 4; ++j) bpj[j] = bprime[cb * 128 + wc * 64 + j * 16 + l15];
#pragma unroll
        for (int i = 0; i < 2; ++i)
#pragma unroll
            for (int j = 0; j < 4; ++j)
#pragma unroll
                for (int r = 0; r < 4; ++r) {
                    int m = wr * 32 + i * 16 + quad * 4 + r;
                    int n = wc * 64 + j * 16 + l15;
                    float v = acc[i][j][r] + bpj[j];
                    v = 0.5f * v * (1.0f + erff(v * 0.70710678118f));
                    hbuf[m * 136 + n] = f2bf(v);
                }
        __syncthreads();
        // read back in A-ownership layout -> hregs (k-cols cb*128..cb*128+127 = kt cb*4..cb*4+3)
#pragma unroll
        for (int ktl = 0; ktl < 4; ++ktl) {
            hregs[cb * 4 + ktl][0] = *(const ushort4*)&hbuf[row0 * 136 + ktl * 32 + f4 * 4];
            hregs[cb * 4 + ktl][1] = *(const ushort4*)&hbuf[(row0 + 32) * 136 + ktl * 32 + f4 * 4];
        }
    }

    // ================= GEMM2: P = H @ W2^T + b2, fused reductions =================
    float psd[2][4], psx[2][4], pdt[2][4];
#pragma unroll
    for (int i = 0; i < 2; ++i)
#pragma unroll
        for (int r = 0; r < 4; ++r) { psd[i][r] = 0.f; psx[i][r] = 0.f; pdt[i][r] = 0.f; }
#pragma unroll
    for (int cb2 = 0; cb2 < 4; ++cb2) {
        f32x4 acc[2][4];
#pragma unroll
        for (int i = 0; i < 2; ++i)
#pragma unroll
            for (int j = 0; j < 4; ++j) acc[i][j] = (f32x4){0.f, 0.f, 0.f, 0.f};
#pragma unroll
        for (int kt = 0; kt < 16; ++kt) {
            __syncthreads();
            *(ushort4*)&Ts[row0 * 40 + f4 * 4]        = hregs[kt][0];
            *(ushort4*)&Ts[(row0 + 32) * 40 + f4 * 4] = hregs[kt][1];
#pragma unroll
            for (int c = 0; c < 2; ++c) {
                int unit = c * 256 + w * 64 + lane;
                int row = unit >> 2, kb = unit & 3;
                load_lds_16(W2b + (size_t)(cb2 * 128 + row) * 512 + kt * 32 + kb * 8,
                            Bs + (size_t)(c * 256 + w * 64) * 8);
            }
            __syncthreads();
            bf16x8 af[2], bfr[4];
            af[0] = *(const bf16x8*)&Ts[(wr * 32 + l15) * 40 + quad * 8];
            af[1] = *(const bf16x8*)&Ts[(wr * 32 + 16 + l15) * 40 + quad * 8];
#pragma unroll
            for (int j = 0; j < 4; ++j)
                bfr[j] = *(const bf16x8*)&Bs[(wc * 64 + j * 16 + l15) * 32 + quad * 8];
#pragma unroll
            for (int i = 0; i < 2; ++i)
#pragma unroll
                for (int j = 0; j < 4; ++j)
                    acc[i][j] = __builtin_amdgcn_mfma_f32_16x16x32_bf16(af[i], bfr[j], acc[i][j], 0, 0, 0);
        }
        // epilogue: accumulate row partials (ssd, nx2, xdot) with fp32 x
        float b2j[4], ej[4];
#pragma unroll
        for (int j = 0; j < 4; ++j) {
            int n = cb2 * 128 + wc * 64 + j * 16 + l15;
            b2j[j] = b2[n];
            ej[j] = ebest[b * 512 + n];
        }
#pragma unroll
        for (int i = 0; i < 2; ++i)
#pragma unroll
            for (int r = 0; r < 4; ++r) {
                int gr = gr0 + wr * 32 + i * 16 + quad * 4 + r;
#pragma unroll
                for (int j = 0; j < 4; ++j) {
                    int n = cb2 * 128 + wc * 64 + j * 16 + l15;
                    float p = acc[i][j][r] + b2j[j];
                    float xv = x[(size_t)gr * 512 + n];
                    float d = xv - p;
                    psd[i][r] += d * d; psx[i][r] += xv * xv; pdt[i][r] += xv * ej[j];
                }
            }
    }
    // ---- reduce over the 16 l15 lanes, stash per-wave row sums ----
#pragma unroll
    for (int i = 0; i < 2; ++i)
#pragma unroll
        for (int r = 0; r < 4; ++r) {
            float sd = psd[i][r], sx = psx[i][r], sdt = pdt[i][r];
#pragma unroll
            for (int m = 8; m >= 1; m >>= 1) {
                sd += __shfl_xor(sd, m);
                sx += __shfl_xor(sx, m);
                sdt += __shfl_xor(sdt, m);
            }
            if (l15 == 0) {
                int rl = i * 16 + quad * 4 + r;
                red[(w * 32 + rl) * 4 + 0] = sd;
                red[(w * 32 + rl) * 4 + 1] = sx;
                red[(w * 32 + rl) * 4 + 2] = sdt;
            }
        }
    __syncthreads();
    // ---- final combine: waves {0,1} cover rows 0..31, {2,3} rows 32..63 ----
    if (t < 64) {
        int rl = t & 31;
        int base = (t >> 5) * 2;
        float sd  = red[((base) * 32 + rl) * 4 + 0] + red[((base + 1) * 32 + rl) * 4 + 0];
        float sx  = red[((base) * 32 + rl) * 4 + 1] + red[((base + 1) * 32 + rl) * 4 + 1];
        float sdt = red[((base) * 32 + rl) * 4 + 2] + red[((base + 1) * 32 + rl) * 4 + 2];
        float ps = sqrtf(sd * (1.0f / 512.0f));
        float ms = max_sim[b];
        float c = 0.f;
        if (ms > 0.3f) {
            float nx = fmaxf(sqrtf(sx), 1e-8f);
            c = 2.0f * (1.0f - sdt / (nx * norm_e[b]));
        }
        out[gr0 + t] = fmaxf(ps, c);
    }
}

extern "C" void kernel_launch(void* const* d_in, const int* in_sizes, int n_in,
                              void* d_out, int out_size, void* d_ws, size_t ws_size,
                              hipStream_t stream) {
    const float* x  = (const float*)d_in[0];
    const float* Wc = (const float*)d_in[1];
    const float* bc = (const float*)d_in[2];
    const float* W1 = (const float*)d_in[3];
    const float* b1 = (const float*)d_in[4];
    const float* W2 = (const float*)d_in[5];
    const float* b2 = (const float*)d_in[6];
    const float* E  = (const float*)d_in[7];
    const float* sl = (const float*)d_in[8];

    char* ws = (char*)d_ws;
    unsigned long long* simkey = (unsigned long long*)(ws + OFF_SIMKEY);
    float* pooled  = (float*)(ws + OFF_POOLED);
    float* max_sim = (float*)(ws + OFF_MAXSIM);
    float* norm_e  = (float*)(ws + OFF_NORME);
    float* ebest   = (float*)(ws + OFF_EBEST);
    float* bprime  = (float*)(ws + OFF_BPRIME);
    unsigned short* Wp  = (unsigned short*)(ws + OFF_WP);
    unsigned short* W2b = (unsigned short*)(ws + OFF_W2B);
    float* out = (float*)d_out;

    hipMemsetAsync(ws, 0, ZEROED_BYTES, stream);
    k_pre<<<1024, 256, 0, stream>>>(W1, Wc, b1, bc, Wp, bprime);
    k_cast<<<256, 256, 0, stream>>>(W2, W2b);
    k_pool<<<dim3(64, 8), 512, 0, stream>>>(x, pooled);
    k_sim<<<2048, 256, 0, stream>>>(E, sl, pooled, simkey);
    k_b2<<<8, 64, 0, stream>>>(E, simkey, max_sim, norm_e, ebest);
    k_fused<<<1024, 256, 0, stream>>>(x, Wp, bprime, W2b, b2, ebest, max_sim, norm_e, out);
}

// Round 3
// 705.263 us; speedup vs baseline: 1.1517x; 1.1250x over previous
//
#include <hip/hip_runtime.h>
#include <math.h>

// ---------------- workspace layout (bytes) ----------------
#define OFF_SIMKEY   0          // u64[8]
#define OFF_POOLED   1024       // f32[8*512]
#define ZEROED_BYTES 17408
#define OFF_MAXSIM   17408      // f32[8]
#define OFF_NORME    17664      // f32[8]
#define OFF_EBEST    17920      // f32[8*512]
#define OFF_BPRIME   34304      // f32[512]
#define OFF_WP       36864      // bf16[512*512]  (W' = W1 @ Wc)
#define OFF_W2B      561152     // bf16[512*512]

typedef __attribute__((ext_vector_type(8))) short bf16x8;
typedef __attribute__((ext_vector_type(4))) float f32x4;

__device__ inline unsigned short f2bf(float f) {
    unsigned int u = __float_as_uint(f);
    unsigned int r = (u + 0x7FFFu + ((u >> 16) & 1u)) >> 16;
    return (unsigned short)r;
}

__device__ inline void load_lds_16(const void* g, void* l) {
    __builtin_amdgcn_global_load_lds((const __attribute__((address_space(1))) void*)g,
                                     (__attribute__((address_space(3))) void*)l, 16, 0, 0);
}

// ---------------- W' = W1 @ Wc (bf16), b' = b1 + W1 @ bc ----------------
__global__ void __launch_bounds__(256) k_pre(const float* __restrict__ W1, const float* __restrict__ Wc,
                      const float* __restrict__ b1, const float* __restrict__ bc,
                      unsigned short* __restrict__ Wp, float* __restrict__ bprime) {
    __shared__ float w1row[512];
    __shared__ float wsum[4];
    int t = threadIdx.x;
    int n = blockIdx.x >> 1, half = blockIdx.x & 1;
    if (t < 128) ((float4*)w1row)[t] = ((const float4*)(W1 + (size_t)n * 512))[t];
    __syncthreads();
    int k = half * 256 + t;
    float acc = 0.f;
#pragma unroll 8
    for (int j = 0; j < 512; ++j) acc += w1row[j] * Wc[(size_t)j * 512 + k];
    Wp[(size_t)n * 512 + k] = f2bf(acc);
    if (half == 0) {
        float p = w1row[t] * bc[t] + w1row[t + 256] * bc[t + 256];
#pragma unroll
        for (int m = 32; m >= 1; m >>= 1) p += __shfl_xor(p, m);
        if ((t & 63) == 0) wsum[t >> 6] = p;
        __syncthreads();
        if (t == 0) bprime[n] = b1[n] + wsum[0] + wsum[1] + wsum[2] + wsum[3];
    }
}

// ---------------- W2 -> bf16 ----------------
__global__ void __launch_bounds__(256) k_cast(const float* __restrict__ W2, unsigned short* __restrict__ W2b) {
    int i = blockIdx.x * 1024 + threadIdx.x * 4;
    float4 v = *(const float4*)(W2 + i);
    ushort4 o;
    o.x = f2bf(v.x); o.y = f2bf(v.y); o.z = f2bf(v.z); o.w = f2bf(v.w);
    *(ushort4*)(W2b + i) = o;
}

// ---------------- pooled sum over L (float4 loads, LDS pre-reduce) ----------------
__global__ void __launch_bounds__(512) k_pool(const float* __restrict__ x, float* __restrict__ pooled) {
    __shared__ float4 pb[4][128];
    int t = threadIdx.x;
    int q = t & 127;      // float4 column group
    int rg = t >> 7;      // row phase 0..3
    int b = blockIdx.y;
    int l0 = blockIdx.x * 128;
    const float4* p = (const float4*)(x + ((size_t)b * 8192 + l0 + rg) * 512) + q;
    float4 s = make_float4(0.f, 0.f, 0.f, 0.f);
#pragma unroll 8
    for (int i = 0; i < 32; ++i) {
        float4 v = p[(size_t)i * 512];   // 4 rows * 128 float4/row
        s.x += v.x; s.y += v.y; s.z += v.z; s.w += v.w;
    }
    pb[rg][q] = s;
    __syncthreads();
    if (rg == 0) {
        float4 a = pb[0][q], b1_ = pb[1][q], c = pb[2][q], d = pb[3][q];
        atomicAdd(&pooled[b * 512 + q * 4 + 0], a.x + b1_.x + c.x + d.x);
        atomicAdd(&pooled[b * 512 + q * 4 + 1], a.y + b1_.y + c.y + d.y);
        atomicAdd(&pooled[b * 512 + q * 4 + 2], a.z + b1_.z + c.z + d.z);
        atomicAdd(&pooled[b * 512 + q * 4 + 3], a.w + b1_.w + c.w + d.w);
    }
}

// ---------------- sim scan: argmax cos(pooled_b, E_s) over active s ----------------
__global__ void __launch_bounds__(256) k_sim(const float* __restrict__ E, const float* __restrict__ sl,
                     const float* __restrict__ pooledws, unsigned long long* __restrict__ simkey) {
    __shared__ float ps[4096];
    __shared__ unsigned long long wkey[4][8];
    int t = threadIdx.x, lane = t & 63, w = t >> 6;
#pragma unroll
    for (int c = 0; c < 16; ++c) ps[t + c * 256] = pooledws[t + c * 256] * (1.0f / 8192.0f);
    __syncthreads();
    float pr[8][8];
#pragma unroll
    for (int b = 0; b < 8; ++b) {
        float4 v0 = *(const float4*)&ps[b * 512 + lane * 8];
        float4 v1 = *(const float4*)&ps[b * 512 + lane * 8 + 4];
        pr[b][0] = v0.x; pr[b][1] = v0.y; pr[b][2] = v0.z; pr[b][3] = v0.w;
        pr[b][4] = v1.x; pr[b][5] = v1.y; pr[b][6] = v1.z; pr[b][7] = v1.w;
    }
    float npinv[8];
#pragma unroll
    for (int b = 0; b < 8; ++b) {
        float s = 0.f;
#pragma unroll
        for (int j = 0; j < 8; ++j) s += pr[b][j] * pr[b][j];
#pragma unroll
        for (int m = 32; m >= 1; m >>= 1) s += __shfl_xor(s, m);
        npinv[b] = 1.0f / fmaxf(sqrtf(s), 1e-8f);
    }
    unsigned long long best[8];
#pragma unroll
    for (int b = 0; b < 8; ++b) best[b] = 0ull;
    int sbase = blockIdx.x * 64 + w * 16;
    float mysl = (lane < 16) ? sl[sbase + lane] : 0.f;
    unsigned long long mask = __ballot(mysl > 0.0f);
    for (int it = 0; it < 16; ++it) {
        if (!((mask >> it) & 1ull)) continue;
        int s = sbase + it;
        const float4* ep = (const float4*)(E + (size_t)s * 512);
        float4 e0 = ep[lane * 2], e1 = ep[lane * 2 + 1];
        float nrm = e0.x * e0.x + e0.y * e0.y + e0.z * e0.z + e0.w * e0.w
                  + e1.x * e1.x + e1.y * e1.y + e1.z * e1.z + e1.w * e1.w;
        float dt[8];
#pragma unroll
        for (int b = 0; b < 8; ++b)
            dt[b] = e0.x * pr[b][0] + e0.y * pr[b][1] + e0.z * pr[b][2] + e0.w * pr[b][3]
                  + e1.x * pr[b][4] + e1.y * pr[b][5] + e1.z * pr[b][6] + e1.w * pr[b][7];
#pragma unroll
        for (int m = 32; m >= 1; m >>= 1) {
            nrm += __shfl_xor(nrm, m);
#pragma unroll
            for (int b = 0; b < 8; ++b) dt[b] += __shfl_xor(dt[b], m);
        }
        float neinv = 1.0f / fmaxf(sqrtf(nrm), 1e-8f);
#pragma unroll
        for (int b = 0; b < 8; ++b) {
            float sim = dt[b] * npinv[b] * neinv;
            unsigned int u = __float_as_uint(sim);
            unsigned int k32 = (u & 0x80000000u) ? ~u : (u | 0x80000000u);
            unsigned long long key = ((unsigned long long)k32 << 32) | (unsigned int)(~(unsigned int)s);
            if (key > best[b]) best[b] = key;
        }
    }
    if (lane == 0) {
#pragma unroll
        for (int b = 0; b < 8; ++b) wkey[w][b] = best[b];
    }
    __syncthreads();
    if (t < 8) {
        unsigned long long k = wkey[0][t];
#pragma unroll
        for (int w2 = 1; w2 < 4; ++w2) if (wkey[w2][t] > k) k = wkey[w2][t];
        if (k) atomicMax(&simkey[t], k);
    }
}

// ---------------- decode best, gather embedding + norm ----------------
__global__ void __launch_bounds__(64) k_b2(const float* __restrict__ E, const unsigned long long* __restrict__ simkey,
                    float* __restrict__ max_sim, float* __restrict__ norm_e, float* __restrict__ ebest) {
    int b = blockIdx.x, lane = threadIdx.x;
    unsigned long long key = simkey[b];
    float ms; unsigned int idx;
    if (key == 0ull) { ms = -1e30f; idx = 0u; }
    else {
        unsigned int k32 = (unsigned int)(key >> 32);
        unsigned int u = (k32 & 0x80000000u) ? (k32 & 0x7FFFFFFFu) : ~k32;
        ms = __uint_as_float(u);
        idx = ~(unsigned int)(key & 0xFFFFFFFFull);
    }
    const float4* ep = (const float4*)(E + (size_t)idx * 512);
    float4 e0 = ep[lane * 2], e1 = ep[lane * 2 + 1];
    *(float4*)&ebest[b * 512 + lane * 8] = e0;
    *(float4*)&ebest[b * 512 + lane * 8 + 4] = e1;
    float s = e0.x * e0.x + e0.y * e0.y + e0.z * e0.z + e0.w * e0.w
            + e1.x * e1.x + e1.y * e1.y + e1.z * e1.z + e1.w * e1.w;
#pragma unroll
    for (int m = 32; m >= 1; m >>= 1) s += __shfl_xor(s, m);
    if (lane == 0) { max_sim[b] = ms; norm_e[b] = fmaxf(sqrtf(s), 1e-8f); }
}

// ---------------- mega: GEMM1(gelu) -> GEMM2 -> reductions -> out ----------------
// 1024 threads (16 waves), BM=64 rows x BN=512 cols per block, 1024 blocks.
// A (bf16 context) = 16 packed dwords/thread in VGPRs; H resides in LDS.
// LDS: Hs ushort[16][64][32] @0 (64K) | Bs ushort[2048*8] @65536 (32K)
//      Ts ushort[64][32] @98304 (4K)  | red f32[64][16][3] @102400 (12K) = 112K total
__global__ void __launch_bounds__(1024, 4) k_mega(
        const float* __restrict__ x, const unsigned short* __restrict__ Wp,
        const float* __restrict__ bprime, const unsigned short* __restrict__ W2b,
        const float* __restrict__ b2, const float* __restrict__ ebest,
        const float* __restrict__ max_sim, const float* __restrict__ norm_e,
        float* __restrict__ out) {
    __shared__ char smem[114688];
    unsigned short* Hs = (unsigned short*)(smem);
    unsigned short* Bs = (unsigned short*)(smem + 65536);
    unsigned short* Ts = (unsigned short*)(smem + 98304);
    unsigned int*  Ts32 = (unsigned int*)Ts;
    float* red = (float*)(smem + 102400);

    const int t = threadIdx.x;
    const int lane = t & 63, w = t >> 6;
    const int l15 = lane & 15, quad = lane >> 4;
    const int r = t >> 4, cp = t & 15;
    const int gr0 = blockIdx.x * 64;
    const int b = gr0 >> 13;

    // ---- preload A: thread owns row r, col pairs {cp+16k}, causal shift ----
    unsigned int areg[16];
    {
        int gr = gr0 + r;
        bool z = ((gr & 8191) == 0);
        const float* src = x + ((size_t)gr - 1) * 512 + cp * 2;
#pragma unroll
        for (int k = 0; k < 16; ++k) {
            float2 v = make_float2(0.f, 0.f);
            if (!z) v = *(const float2*)(src + k * 32);
            areg[k] = (unsigned int)f2bf(v.x) | ((unsigned int)f2bf(v.y) << 16);
        }
    }

    // ================= GEMM1: H = gelu(A @ Wp^T + b') =================
    f32x4 acc[4][2];
#pragma unroll
    for (int i = 0; i < 4; ++i)
#pragma unroll
        for (int j = 0; j < 2; ++j) acc[i][j] = (f32x4){0.f, 0.f, 0.f, 0.f};
#pragma unroll
    for (int kt = 0; kt < 16; ++kt) {
        __syncthreads();
        Ts32[r * 16 + cp] = areg[kt];
#pragma unroll
        for (int c = 0; c < 2; ++c) {
            int unit = c * 1024 + t;
            load_lds_16(Wp + (size_t)(unit >> 2) * 512 + kt * 32 + (unit & 3) * 8,
                        Bs + c * 8192 + w * 512);
        }
        __syncthreads();
        bf16x8 af[4], bfr[2];
#pragma unroll
        for (int i = 0; i < 4; ++i)
            af[i] = *(const bf16x8*)&Ts[(i * 16 + l15) * 32 + quad * 8];
#pragma unroll
        for (int j = 0; j < 2; ++j)
            bfr[j] = *(const bf16x8*)&Bs[(w * 32 + j * 16 + l15) * 32 + quad * 8];
#pragma unroll
        for (int i = 0; i < 4; ++i)
#pragma unroll
            for (int j = 0; j < 2; ++j)
                acc[i][j] = __builtin_amdgcn_mfma_f32_16x16x32_bf16(af[i], bfr[j], acc[i][j], 0, 0, 0);
    }
    // epilogue: bias + exact gelu -> Hs (kt-tiled layout [n>>5][m][n&31])
    {
        float bpj[2];
#pragma unroll
        for (int j = 0; j < 2; ++j) bpj[j] = bprime[w * 32 + j * 16 + l15];
#pragma unroll
        for (int i = 0; i < 4; ++i)
#pragma unroll
            for (int j = 0; j < 2; ++j)
#pragma unroll
                for (int rg = 0; rg < 4; ++rg) {
                    int m = i * 16 + quad * 4 + rg;
                    int n = w * 32 + j * 16 + l15;
                    float v = acc[i][j][rg] + bpj[j];
                    v = 0.5f * v * (1.0f + erff(v * 0.70710678118f));
                    Hs[(n >> 5) * 2048 + m * 32 + (n & 31)] = f2bf(v);
                }
    }

    // ================= GEMM2: P = H @ W2^T + b2 =================
    f32x4 acc2[4][2];
#pragma unroll
    for (int i = 0; i < 4; ++i)
#pragma unroll
        for (int j = 0; j < 2; ++j) acc2[i][j] = (f32x4){0.f, 0.f, 0.f, 0.f};
#pragma unroll
    for (int kt = 0; kt < 16; ++kt) {
        __syncthreads();
#pragma unroll
        for (int c = 0; c < 2; ++c) {
            int unit = c * 1024 + t;
            load_lds_16(W2b + (size_t)(unit >> 2) * 512 + kt * 32 + (unit & 3) * 8,
                        Bs + c * 8192 + w * 512);
        }
        __syncthreads();
        bf16x8 af[4], bfr[2];
#pragma unroll
        for (int i = 0; i < 4; ++i)
            af[i] = *(const bf16x8*)&Hs[kt * 2048 + (i * 16 + l15) * 32 + quad * 8];
#pragma unroll
        for (int j = 0; j < 2; ++j)
            bfr[j] = *(const bf16x8*)&Bs[(w * 32 + j * 16 + l15) * 32 + quad * 8];
#pragma unroll
        for (int i = 0; i < 4; ++i)
#pragma unroll
            for (int j = 0; j < 2; ++j)
                acc2[i][j] = __builtin_amdgcn_mfma_f32_16x16x32_bf16(af[i], bfr[j], acc2[i][j], 0, 0, 0);
    }

    // epilogue: ssd / nx2 / xdot partials with fp32 x, cross-wave reduce in LDS
    {
        float b2j[2], ej[2];
#pragma unroll
        for (int j = 0; j < 2; ++j) {
            int n = w * 32 + j * 16 + l15;
            b2j[j] = b2[n];
            ej[j] = ebest[b * 512 + n];
        }
#pragma unroll
        for (int i = 0; i < 4; ++i)
#pragma unroll
            for (int rg = 0; rg < 4; ++rg) {
                int m = i * 16 + quad * 4 + rg;
                int gr = gr0 + m;
                float sd = 0.f, sx = 0.f, sdt = 0.f;
#pragma unroll
                for (int j = 0; j < 2; ++j) {
                    int n = w * 32 + j * 16 + l15;
                    float p = acc2[i][j][rg] + b2j[j];
                    float xv = x[(size_t)gr * 512 + n];
                    float d = xv - p;
                    sd += d * d; sx += xv * xv; sdt += xv * ej[j];
                }
#pragma unroll
                for (int mm = 8; mm >= 1; mm >>= 1) {
                    sd += __shfl_xor(sd, mm);
                    sx += __shfl_xor(sx, mm);
                    sdt += __shfl_xor(sdt, mm);
                }
                if (l15 == 0) {
                    red[(m * 16 + w) * 3 + 0] = sd;
                    red[(m * 16 + w) * 3 + 1] = sx;
                    red[(m * 16 + w) * 3 + 2] = sdt;
                }
            }
    }
    __syncthreads();
    if (t < 64) {
        float sd = 0.f, sx = 0.f, sdt = 0.f;
#pragma unroll
        for (int w2 = 0; w2 < 16; ++w2) {
            sd  += red[(t * 16 + w2) * 3 + 0];
            sx  += red[(t * 16 + w2) * 3 + 1];
            sdt += red[(t * 16 + w2) * 3 + 2];
        }
        float ps = sqrtf(sd * (1.0f / 512.0f));
        float ms = max_sim[b];
        float c = 0.f;
        if (ms > 0.3f) {
            float nx = fmaxf(sqrtf(sx), 1e-8f);
            c = 2.0f * (1.0f - sdt / (nx * norm_e[b]));
        }
        out[gr0 + t] = fmaxf(ps, c);
    }
}

extern "C" void kernel_launch(void* const* d_in, const int* in_sizes, int n_in,
                              void* d_out, int out_size, void* d_ws, size_t ws_size,
                              hipStream_t stream) {
    const float* x  = (const float*)d_in[0];
    const float* Wc = (const float*)d_in[1];
    const float* bc = (const float*)d_in[2];
    const float* W1 = (const float*)d_in[3];
    const float* b1 = (const float*)d_in[4];
    const float* W2 = (const float*)d_in[5];
    const float* b2 = (const float*)d_in[6];
    const float* E  = (const float*)d_in[7];
    const float* sl = (const float*)d_in[8];

    char* ws = (char*)d_ws;
    unsigned long long* simkey = (unsigned long long*)(ws + OFF_SIMKEY);
    float* pooled  = (float*)(ws + OFF_POOLED);
    float* max_sim = (float*)(ws + OFF_MAXSIM);
    float* norm_e  = (float*)(ws + OFF_NORME);
    float* ebest   = (float*)(ws + OFF_EBEST);
    float* bprime  = (float*)(ws + OFF_BPRIME);
    unsigned short* Wp  = (unsigned short*)(ws + OFF_WP);
    unsigned short* W2b = (unsigned short*)(ws + OFF_W2B);
    float* out = (float*)d_out;

    hipMemsetAsync(ws, 0, ZEROED_BYTES, stream);
    k_pre<<<1024, 256, 0, stream>>>(W1, Wc, b1, bc, Wp, bprime);
    k_cast<<<256, 256, 0, stream>>>(W2, W2b);
    k_pool<<<dim3(64, 8), 512, 0, stream>>>(x, pooled);
    k_sim<<<2048, 256, 0, stream>>>(E, sl, pooled, simkey);
    k_b2<<<8, 64, 0, stream>>>(E, simkey, max_sim, norm_e, ebest);
    k_mega<<<1024, 1024, 0, stream>>>(x, Wp, bprime, W2b, b2, ebest, max_sim, norm_e, out);
}

// Round 4
// 657.574 us; speedup vs baseline: 1.2352x; 1.0725x over previous
//
#include <hip/hip_runtime.h>
#include <math.h>

// ---------------- workspace layout (bytes) ----------------
#define OFF_SIMKEY   0          // u64[8]
#define OFF_POOLED   1024       // f32[8*512]
#define ZEROED_BYTES 17408
#define OFF_MAXSIM   17408      // f32[8]
#define OFF_NORME    17664      // f32[8]
#define OFF_EBEST    17920      // f32[8*512]
#define OFF_BPRIME   34304      // f32[512]
#define OFF_WP       36864      // bf16[512*512]  (W' = W1 @ Wc)
#define OFF_W2B      561152     // bf16[512*512]

typedef __attribute__((ext_vector_type(8))) short bf16x8;
typedef __attribute__((ext_vector_type(4))) float f32x4;

__device__ inline unsigned short f2bf(float f) {
    unsigned int u = __float_as_uint(f);
    unsigned int r = (u + 0x7FFFu + ((u >> 16) & 1u)) >> 16;
    return (unsigned short)r;
}

__device__ inline void load_lds_16(const void* g, void* l) {
    __builtin_amdgcn_global_load_lds((const __attribute__((address_space(1))) void*)g,
                                     (__attribute__((address_space(3))) void*)l, 16, 0, 0);
}

// ---------------- W' = W1 @ Wc (bf16), b' = b1 + W1 @ bc ----------------
__global__ void __launch_bounds__(256) k_pre(const float* __restrict__ W1, const float* __restrict__ Wc,
                      const float* __restrict__ b1, const float* __restrict__ bc,
                      unsigned short* __restrict__ Wp, float* __restrict__ bprime) {
    __shared__ float w1row[512];
    __shared__ float wsum[4];
    int t = threadIdx.x;
    int n = blockIdx.x >> 1, half = blockIdx.x & 1;
    if (t < 128) ((float4*)w1row)[t] = ((const float4*)(W1 + (size_t)n * 512))[t];
    __syncthreads();
    int k = half * 256 + t;
    float acc = 0.f;
#pragma unroll 8
    for (int j = 0; j < 512; ++j) acc += w1row[j] * Wc[(size_t)j * 512 + k];
    Wp[(size_t)n * 512 + k] = f2bf(acc);
    if (half == 0) {
        float p = w1row[t] * bc[t] + w1row[t + 256] * bc[t + 256];
#pragma unroll
        for (int m = 32; m >= 1; m >>= 1) p += __shfl_xor(p, m);
        if ((t & 63) == 0) wsum[t >> 6] = p;
        __syncthreads();
        if (t == 0) bprime[n] = b1[n] + wsum[0] + wsum[1] + wsum[2] + wsum[3];
    }
}

// ---------------- W2 -> bf16 ----------------
__global__ void __launch_bounds__(256) k_cast(const float* __restrict__ W2, unsigned short* __restrict__ W2b) {
    int i = blockIdx.x * 1024 + threadIdx.x * 4;
    float4 v = *(const float4*)(W2 + i);
    ushort4 o;
    o.x = f2bf(v.x); o.y = f2bf(v.y); o.z = f2bf(v.z); o.w = f2bf(v.w);
    *(ushort4*)(W2b + i) = o;
}

// ---------------- pooled sum over L (float4 loads, LDS pre-reduce) ----------------
__global__ void __launch_bounds__(512) k_pool(const float* __restrict__ x, float* __restrict__ pooled) {
    __shared__ float4 pb[4][128];
    int t = threadIdx.x;
    int q = t & 127;
    int rg = t >> 7;
    int b = blockIdx.y;
    int l0 = blockIdx.x * 128;
    const float4* p = (const float4*)(x + ((size_t)b * 8192 + l0 + rg) * 512) + q;
    float4 s = make_float4(0.f, 0.f, 0.f, 0.f);
#pragma unroll 8
    for (int i = 0; i < 32; ++i) {
        float4 v = p[(size_t)i * 512];
        s.x += v.x; s.y += v.y; s.z += v.z; s.w += v.w;
    }
    pb[rg][q] = s;
    __syncthreads();
    if (rg == 0) {
        float4 a = pb[0][q], b1_ = pb[1][q], c = pb[2][q], d = pb[3][q];
        atomicAdd(&pooled[b * 512 + q * 4 + 0], a.x + b1_.x + c.x + d.x);
        atomicAdd(&pooled[b * 512 + q * 4 + 1], a.y + b1_.y + c.y + d.y);
        atomicAdd(&pooled[b * 512 + q * 4 + 2], a.z + b1_.z + c.z + d.z);
        atomicAdd(&pooled[b * 512 + q * 4 + 3], a.w + b1_.w + c.w + d.w);
    }
}

// ---------------- sim scan: argmax cos(pooled_b, E_s) over active s ----------------
__global__ void __launch_bounds__(256) k_sim(const float* __restrict__ E, const float* __restrict__ sl,
                     const float* __restrict__ pooledws, unsigned long long* __restrict__ simkey) {
    __shared__ float ps[4096];
    __shared__ unsigned long long wkey[4][8];
    int t = threadIdx.x, lane = t & 63, w = t >> 6;
#pragma unroll
    for (int c = 0; c < 16; ++c) ps[t + c * 256] = pooledws[t + c * 256] * (1.0f / 8192.0f);
    __syncthreads();
    float pr[8][8];
#pragma unroll
    for (int b = 0; b < 8; ++b) {
        float4 v0 = *(const float4*)&ps[b * 512 + lane * 8];
        float4 v1 = *(const float4*)&ps[b * 512 + lane * 8 + 4];
        pr[b][0] = v0.x; pr[b][1] = v0.y; pr[b][2] = v0.z; pr[b][3] = v0.w;
        pr[b][4] = v1.x; pr[b][5] = v1.y; pr[b][6] = v1.z; pr[b][7] = v1.w;
    }
    float npinv[8];
#pragma unroll
    for (int b = 0; b < 8; ++b) {
        float s = 0.f;
#pragma unroll
        for (int j = 0; j < 8; ++j) s += pr[b][j] * pr[b][j];
#pragma unroll
        for (int m = 32; m >= 1; m >>= 1) s += __shfl_xor(s, m);
        npinv[b] = 1.0f / fmaxf(sqrtf(s), 1e-8f);
    }
    unsigned long long best[8];
#pragma unroll
    for (int b = 0; b < 8; ++b) best[b] = 0ull;
    int sbase = blockIdx.x * 64 + w * 16;
    float mysl = (lane < 16) ? sl[sbase + lane] : 0.f;
    unsigned long long mask = __ballot(mysl > 0.0f);
    for (int it = 0; it < 16; ++it) {
        if (!((mask >> it) & 1ull)) continue;
        int s = sbase + it;
        const float4* ep = (const float4*)(E + (size_t)s * 512);
        float4 e0 = ep[lane * 2], e1 = ep[lane * 2 + 1];
        float nrm = e0.x * e0.x + e0.y * e0.y + e0.z * e0.z + e0.w * e0.w
                  + e1.x * e1.x + e1.y * e1.y + e1.z * e1.z + e1.w * e1.w;
        float dt[8];
#pragma unroll
        for (int b = 0; b < 8; ++b)
            dt[b] = e0.x * pr[b][0] + e0.y * pr[b][1] + e0.z * pr[b][2] + e0.w * pr[b][3]
                  + e1.x * pr[b][4] + e1.y * pr[b][5] + e1.z * pr[b][6] + e1.w * pr[b][7];
#pragma unroll
        for (int m = 32; m >= 1; m >>= 1) {
            nrm += __shfl_xor(nrm, m);
#pragma unroll
            for (int b = 0; b < 8; ++b) dt[b] += __shfl_xor(dt[b], m);
        }
        float neinv = 1.0f / fmaxf(sqrtf(nrm), 1e-8f);
#pragma unroll
        for (int b = 0; b < 8; ++b) {
            float sim = dt[b] * npinv[b] * neinv;
            unsigned int u = __float_as_uint(sim);
            unsigned int k32 = (u & 0x80000000u) ? ~u : (u | 0x80000000u);
            unsigned long long key = ((unsigned long long)k32 << 32) | (unsigned int)(~(unsigned int)s);
            if (key > best[b]) best[b] = key;
        }
    }
    if (lane == 0) {
#pragma unroll
        for (int b = 0; b < 8; ++b) wkey[w][b] = best[b];
    }
    __syncthreads();
    if (t < 8) {
        unsigned long long k = wkey[0][t];
#pragma unroll
        for (int w2 = 1; w2 < 4; ++w2) if (wkey[w2][t] > k) k = wkey[w2][t];
        if (k) atomicMax(&simkey[t], k);
    }
}

// ---------------- decode best, gather embedding + norm ----------------
__global__ void __launch_bounds__(64) k_b2(const float* __restrict__ E, const unsigned long long* __restrict__ simkey,
                    float* __restrict__ max_sim, float* __restrict__ norm_e, float* __restrict__ ebest) {
    int b = blockIdx.x, lane = threadIdx.x;
    unsigned long long key = simkey[b];
    float ms; unsigned int idx;
    if (key == 0ull) { ms = -1e30f; idx = 0u; }
    else {
        unsigned int k32 = (unsigned int)(key >> 32);
        unsigned int u = (k32 & 0x80000000u) ? (k32 & 0x7FFFFFFFu) : ~k32;
        ms = __uint_as_float(u);
        idx = ~(unsigned int)(key & 0xFFFFFFFFull);
    }
    const float4* ep = (const float4*)(E + (size_t)idx * 512);
    float4 e0 = ep[lane * 2], e1 = ep[lane * 2 + 1];
    *(float4*)&ebest[b * 512 + lane * 8] = e0;
    *(float4*)&ebest[b * 512 + lane * 8 + 4] = e1;
    float s = e0.x * e0.x + e0.y * e0.y + e0.z * e0.z + e0.w * e0.w
            + e1.x * e1.x + e1.y * e1.y + e1.z * e1.z + e1.w * e1.w;
#pragma unroll
    for (int m = 32; m >= 1; m >>= 1) s += __shfl_xor(s, m);
    if (lane == 0) { max_sim[b] = ms; norm_e[b] = fmaxf(sqrtf(s), 1e-8f); }
}

// ---------------- mega v2: swizzled LDS + double-buffered staging ----------------
// 512 threads (8 waves), BM=64 x BN=512, 64x64 wave-tiles. 1024 blocks.
// LDS: Hs 64K @0 | Bs 2x32K @65536 | Ts 2x4K @131072 | red 6K @139264 = 145408.
// All fragment reads 2-way-conflict-free via group ^= f(row) XOR swizzle;
// Bs is swizzled by permuting the per-lane global source of global_load_lds.
__global__ void __launch_bounds__(512, 2) k_mega(
        const float* __restrict__ x, const unsigned short* __restrict__ Wp,
        const float* __restrict__ bprime, const unsigned short* __restrict__ W2b,
        const float* __restrict__ b2, const float* __restrict__ ebest,
        const float* __restrict__ max_sim, const float* __restrict__ norm_e,
        float* __restrict__ out) {
    __shared__ char smem[145408];
    unsigned short* Hs = (unsigned short*)(smem);
    unsigned short* Bs = (unsigned short*)(smem + 65536);
    unsigned int*  Ts32 = (unsigned int*)(smem + 131072);
    unsigned short* Ts = (unsigned short*)(smem + 131072);
    float* red = (float*)(smem + 139264);

    const int t = threadIdx.x;
    const int lane = t & 63, w = t >> 6;
    const int l15 = lane & 15, quad = lane >> 4;
    const int gr0 = blockIdx.x * 64;
    const int b = gr0 >> 13;

    // ---- staging geometry (precomputed) ----
    // B staging: 4 chunks, lane-permuted source so LDS lands swizzled
    int srcB[4];
#pragma unroll
    for (int c = 0; c < 4; ++c) {
        int off16 = c * 512 + t;
        int row = off16 >> 2, slot = off16 & 3;
        int g = slot ^ ((row >> 1) & 3);
        srcB[c] = row * 512 + g * 8;
    }
    // Ts write slots: thread owns row r = t>>3, dword pair {c, c+8}
    const int r = t >> 3, cc = t & 7;
    const int sR = (r >> 1) & 3;
    const int d0 = (((cc >> 2) ^ sR) << 2) | (cc & 3);
    const int d1 = ((((cc >> 2) + 2) ^ sR) << 2) | (cc & 3);
    // fragment read offsets (ushort units, swizzled)
    int tsoff[4], bsoff[4], hoff[4];
#pragma unroll
    for (int i = 0; i < 4; ++i) {
        int rowA = i * 16 + l15;
        tsoff[i] = rowA * 32 + ((quad ^ ((rowA >> 1) & 3)) << 3);
        hoff[i]  = rowA * 32 + ((quad ^ ((rowA >> 2) & 3)) << 3);
        int rowB = w * 64 + i * 16 + l15;
        bsoff[i] = rowB * 32 + ((quad ^ ((rowB >> 1) & 3)) << 3);
    }

    // ---- A preload: row r, cols {2cc,2cc+1} and {2cc+16,2cc+17} per kt ----
    unsigned int alo[16], ahi[16];
    {
        int gr = gr0 + r;
        bool z = ((gr & 8191) == 0);
        const float* src = x + ((size_t)gr - 1) * 512 + cc * 2;
#pragma unroll
        for (int kt = 0; kt < 16; ++kt) {
            float2 v0 = make_float2(0.f, 0.f), v1 = make_float2(0.f, 0.f);
            if (!z) { v0 = *(const float2*)(src + kt * 32); v1 = *(const float2*)(src + kt * 32 + 16); }
            alo[kt] = (unsigned int)f2bf(v0.x) | ((unsigned int)f2bf(v0.y) << 16);
            ahi[kt] = (unsigned int)f2bf(v1.x) | ((unsigned int)f2bf(v1.y) << 16);
        }
    }

    // ---- GEMM1 preamble: stage kt=0 ----
    Ts32[r * 16 + d0] = alo[0];
    Ts32[r * 16 + d1] = ahi[0];
#pragma unroll
    for (int c = 0; c < 4; ++c)
        load_lds_16(Wp + srcB[c], Bs + c * 4096 + w * 512);
    __syncthreads();

    // ================= GEMM1 K-loop =================
    f32x4 acc[4][4];
#pragma unroll
    for (int i = 0; i < 4; ++i)
#pragma unroll
        for (int j = 0; j < 4; ++j) acc[i][j] = (f32x4){0.f, 0.f, 0.f, 0.f};
#pragma unroll
    for (int kt = 0; kt < 16; ++kt) {
        const int cur = kt & 1, nxt = cur ^ 1;
        if (kt < 15) {
            Ts32[nxt * 1024 + r * 16 + d0] = alo[kt + 1];
            Ts32[nxt * 1024 + r * 16 + d1] = ahi[kt + 1];
#pragma unroll
            for (int c = 0; c < 4; ++c)
                load_lds_16(Wp + srcB[c] + (kt + 1) * 32, Bs + nxt * 16384 + c * 4096 + w * 512);
        } else {
#pragma unroll
            for (int c = 0; c < 4; ++c)
                load_lds_16(W2b + srcB[c], Bs + c * 4096 + w * 512);  // GEMM2 kt=0 prefetch -> buf0
        }
        bf16x8 af[4], bfr[4];
#pragma unroll
        for (int i = 0; i < 4; ++i) af[i] = *(const bf16x8*)&Ts[cur * 2048 + tsoff[i]];
#pragma unroll
        for (int j = 0; j < 4; ++j) bfr[j] = *(const bf16x8*)&Bs[cur * 16384 + bsoff[j]];
#pragma unroll
        for (int i = 0; i < 4; ++i)
#pragma unroll
            for (int j = 0; j < 4; ++j)
                acc[i][j] = __builtin_amdgcn_mfma_f32_16x16x32_bf16(af[i], bfr[j], acc[i][j], 0, 0, 0);
        __syncthreads();
    }

    // ---- GEMM1 epilogue: bias + exact gelu -> Hs (swizzled) ----
    {
        float bpj[4];
#pragma unroll
        for (int j = 0; j < 4; ++j) bpj[j] = bprime[w * 64 + j * 16 + l15];
#pragma unroll
        for (int i = 0; i < 4; ++i)
#pragma unroll
            for (int j = 0; j < 4; ++j)
#pragma unroll
                for (int rg = 0; rg < 4; ++rg) {
                    int m = i * 16 + quad * 4 + rg;
                    int ktc = w * 2 + (j >> 1);
                    int grp = ((j & 1) * 2 + (l15 >> 3)) ^ ((m >> 2) & 3);
                    float v = acc[i][j][rg] + bpj[j];
                    v = 0.5f * v * (1.0f + erff(v * 0.70710678118f));
                    Hs[ktc * 2048 + m * 32 + grp * 8 + (l15 & 7)] = f2bf(v);
                }
    }
    __syncthreads();

    // ================= GEMM2 K-loop =================
    f32x4 acc2[4][4];
#pragma unroll
    for (int i = 0; i < 4; ++i)
#pragma unroll
        for (int j = 0; j < 4; ++j) acc2[i][j] = (f32x4){0.f, 0.f, 0.f, 0.f};
#pragma unroll
    for (int kt = 0; kt < 16; ++kt) {
        const int cur = kt & 1, nxt = cur ^ 1;
        if (kt < 15) {
#pragma unroll
            for (int c = 0; c < 4; ++c)
                load_lds_16(W2b + srcB[c] + (kt + 1) * 32, Bs + nxt * 16384 + c * 4096 + w * 512);
        }
        bf16x8 af[4], bfr[4];
#pragma unroll
        for (int i = 0; i < 4; ++i) af[i] = *(const bf16x8*)&Hs[kt * 2048 + hoff[i]];
#pragma unroll
        for (int j = 0; j < 4; ++j) bfr[j] = *(const bf16x8*)&Bs[cur * 16384 + bsoff[j]];
#pragma unroll
        for (int i = 0; i < 4; ++i)
#pragma unroll
            for (int j = 0; j < 4; ++j)
                acc2[i][j] = __builtin_amdgcn_mfma_f32_16x16x32_bf16(af[i], bfr[j], acc2[i][j], 0, 0, 0);
        if (kt < 15) __syncthreads();
    }

    // ---- GEMM2 epilogue: ssd/nx2/xdot partials, cross-wave reduce, out ----
    {
        float b2j[4], ej[4];
#pragma unroll
        for (int j = 0; j < 4; ++j) {
            int n = w * 64 + j * 16 + l15;
            b2j[j] = b2[n];
            ej[j] = ebest[b * 512 + n];
        }
#pragma unroll
        for (int i = 0; i < 4; ++i)
#pragma unroll
            for (int rg = 0; rg < 4; ++rg) {
                int m = i * 16 + quad * 4 + rg;
                int gr = gr0 + m;
                float sd = 0.f, sx = 0.f, sdt = 0.f;
#pragma unroll
                for (int j = 0; j < 4; ++j) {
                    int n = w * 64 + j * 16 + l15;
                    float p = acc2[i][j][rg] + b2j[j];
                    float xv = x[(size_t)gr * 512 + n];
                    float d = xv - p;
                    sd += d * d; sx += xv * xv; sdt += xv * ej[j];
                }
#pragma unroll
                for (int mm = 8; mm >= 1; mm >>= 1) {
                    sd += __shfl_xor(sd, mm);
                    sx += __shfl_xor(sx, mm);
                    sdt += __shfl_xor(sdt, mm);
                }
                if (l15 == 0) {
                    red[(m * 8 + w) * 3 + 0] = sd;
                    red[(m * 8 + w) * 3 + 1] = sx;
                    red[(m * 8 + w) * 3 + 2] = sdt;
                }
            }
    }
    __syncthreads();
    if (t < 64) {
        float sd = 0.f, sx = 0.f, sdt = 0.f;
#pragma unroll
        for (int w2 = 0; w2 < 8; ++w2) {
            sd  += red[(t * 8 + w2) * 3 + 0];
            sx  += red[(t * 8 + w2) * 3 + 1];
            sdt += red[(t * 8 + w2) * 3 + 2];
        }
        float ps = sqrtf(sd * (1.0f / 512.0f));
        float ms = max_sim[b];
        float c = 0.f;
        if (ms > 0.3f) {
            float nx = fmaxf(sqrtf(sx), 1e-8f);
            c = 2.0f * (1.0f - sdt / (nx * norm_e[b]));
        }
        out[gr0 + t] = fmaxf(ps, c);
    }
}

extern "C" void kernel_launch(void* const* d_in, const int* in_sizes, int n_in,
                              void* d_out, int out_size, void* d_ws, size_t ws_size,
                              hipStream_t stream) {
    const float* x  = (const float*)d_in[0];
    const float* Wc = (const float*)d_in[1];
    const float* bc = (const float*)d_in[2];
    const float* W1 = (const float*)d_in[3];
    const float* b1 = (const float*)d_in[4];
    const float* W2 = (const float*)d_in[5];
    const float* b2 = (const float*)d_in[6];
    const float* E  = (const float*)d_in[7];
    const float* sl = (const float*)d_in[8];

    char* ws = (char*)d_ws;
    unsigned long long* simkey = (unsigned long long*)(ws + OFF_SIMKEY);
    float* pooled  = (float*)(ws + OFF_POOLED);
    float* max_sim = (float*)(ws + OFF_MAXSIM);
    float* norm_e  = (float*)(ws + OFF_NORME);
    float* ebest   = (float*)(ws + OFF_EBEST);
    float* bprime  = (float*)(ws + OFF_BPRIME);
    unsigned short* Wp  = (unsigned short*)(ws + OFF_WP);
    unsigned short* W2b = (unsigned short*)(ws + OFF_W2B);
    float* out = (float*)d_out;

    hipMemsetAsync(ws, 0, ZEROED_BYTES, stream);
    k_pre<<<1024, 256, 0, stream>>>(W1, Wc, b1, bc, Wp, bprime);
    k_cast<<<256, 256, 0, stream>>>(W2, W2b);
    k_pool<<<dim3(64, 8), 512, 0, stream>>>(x, pooled);
    k_sim<<<2048, 256, 0, stream>>>(E, sl, pooled, simkey);
    k_b2<<<8, 64, 0, stream>>>(E, simkey, max_sim, norm_e, ebest);
    k_mega<<<1024, 512, 0, stream>>>(x, Wp, bprime, W2b, b2, ebest, max_sim, norm_e, out);
}